// Round 8
// baseline (50.468 us; speedup 1.0000x reference)
//
#include <hip/hip_runtime.h>

#define Bc   2
#define Cc   256
#define Hc   200
#define Wc   200
#define NROI 512
#define NBIN 49
#define HWn  (Hc * Wc)
#define LSTRIDE 260   // floats; 49*260*4 = 50,960 B LDS in main kernel
#define MAP_BYTES ((size_t)Bc * HWn * Cc * 2)

// ---- bf16 helpers (RNE) ----
__device__ inline unsigned short f2bf(float f) {
    unsigned int u = __float_as_uint(f);
    return (unsigned short)((u + 0x7FFFu + ((u >> 16) & 1u)) >> 16);
}
__device__ inline float bf2f(unsigned short u) {
    return __uint_as_float(((unsigned int)u) << 16);
}

struct RoiParams { int b; float cx, cy, rw, rh, cs, sn, bh, bw; };

__device__ inline RoiParams load_roi(const float* rois, int n) {
    RoiParams p;
    const float* r = rois + n * 6;
    p.b  = (int)r[0];
    p.cx = r[1] * 0.25f;  p.cy = r[2] * 0.25f;
    p.rw = fmaxf(r[3] * 0.25f, 1.0f);
    p.rh = fmaxf(r[4] * 0.25f, 1.0f);
    p.cs = cosf(r[5]);    p.sn = sinf(r[5]);
    p.bh = p.rh * (1.0f / 7.0f);
    p.bw = p.rw * (1.0f / 7.0f);
    return p;
}

// per-sample coords -> 4 corner weights (validity+mean folded) + 4 pixel indices
__device__ inline void sample_wix(const RoiParams& p, int ph, int pw, int s,
                                  float* wt, int* pix) {
    const float sy = (s >> 1) ? 0.75f : 0.25f;
    const float sx = (s & 1)  ? 0.75f : 0.25f;
    const float yy = -0.5f * p.rh + ((float)ph + sy) * p.bh;
    const float xx = -0.5f * p.rw + ((float)pw + sx) * p.bw;
    float y = yy * p.cs - xx * p.sn + p.cy;
    float x = yy * p.sn + xx * p.cs + p.cx;
    const bool valid = (y > -1.0f) && (y < (float)Hc) && (x > -1.0f) && (x < (float)Wc);
    y = fmaxf(y, 0.0f); x = fmaxf(x, 0.0f);
    int yl = (int)y, xl = (int)x;
    const bool hiy = yl >= Hc - 1, hix = xl >= Wc - 1;
    yl = min(yl, Hc - 1); xl = min(xl, Wc - 1);
    const int yh = hiy ? (Hc - 1) : (yl + 1);
    const int xh = hix ? (Wc - 1) : (xl + 1);
    const float ly = hiy ? 0.0f : (y - (float)yl);
    const float lx = hix ? 0.0f : (x - (float)xl);
    const float hy = 1.0f - ly, hx = 1.0f - lx;
    const float vm = valid ? 0.25f : 0.0f;
    wt[0] = vm * hy * hx;  wt[1] = vm * hy * lx;
    wt[2] = vm * ly * hx;  wt[3] = vm * ly * lx;
    const int rl = (p.b * Hc + yl) * Wc;
    const int rt = (p.b * Hc + yh) * Wc;
    pix[0] = rl + xl;  pix[1] = rl + xh;
    pix[2] = rt + xl;  pix[3] = rt + xh;
}

// ---------------- roi scheduling: counting sort by (batch, cy-band) ----------------
// One block, 512 threads (1 per roi). perm[rank] = roi, rank sorted by bucket.
__global__ __launch_bounds__(512) void sort_rois(const float* __restrict__ rois,
                                                 int* __restrict__ perm) {
    __shared__ int hist[256];
    __shared__ int base[256];
    const int t = threadIdx.x;
    if (t < 256) hist[t] = 0;
    __syncthreads();

    const float* r = rois + t * 6;
    const int   b  = (int)r[0];
    const float cy = r[2] * 0.25f;                       // ~[15,185]
    int band = (int)(cy * (127.0f / 200.0f));
    band = min(max(band, 0), 127);
    const int bucket = b * 128 + band;
    atomicAdd(&hist[bucket], 1);
    __syncthreads();

    if (t == 0) {
        int acc = 0;
        for (int i = 0; i < 256; ++i) { base[i] = acc; acc += hist[i]; }
    }
    __syncthreads();

    const int rank = atomicAdd(&base[bucket], 1);
    perm[rank] = t;
}

// ---------------- NCHW fp32 -> NHWC bf16 transpose (64x64 LDS tile) ----------------
__global__ __launch_bounds__(256) void transpose_to_bf16_nhwc(const float* __restrict__ in,
                                                              unsigned short* __restrict__ out) {
    __shared__ unsigned short tile[64][65];
    const int b   = blockIdx.z;
    const int hw0 = blockIdx.x * 64;
    const int c0  = blockIdx.y * 64;
    const int tx  = threadIdx.x & 63;
    const int ty  = threadIdx.x >> 6;

    #pragma unroll
    for (int i = ty; i < 64; i += 4) {
        float v = in[(size_t)(b * Cc + c0 + i) * HWn + hw0 + tx];
        tile[i][tx] = f2bf(v);   // channel = c0+i, hw = hw0+tx
    }
    __syncthreads();

    const int j  = threadIdx.x & 31;    // channel pair -> c0+2j, c0+2j+1
    const int r0 = threadIdx.x >> 5;    // 0..7
    unsigned int* out32 = (unsigned int*)out;
    #pragma unroll
    for (int r = r0; r < 64; r += 8) {
        unsigned int lo = tile[2 * j][r];
        unsigned int hi = tile[2 * j + 1][r];
        out32[((size_t)(b * HWn + hw0 + r) * Cc + c0) / 2 + j] = lo | (hi << 16);
    }
}

// ---------------- main kernel (round-4 body + XCD-banded roi assignment) ----------------
// 512 blocks (1 per roi) of 512 thr (8 waves). Block bid -> roi perm[(bid&7)*64 + bid/8]:
// XCD bid%8 hosts a contiguous sorted chunk (one batch, ~43-row cy band, ~6 MB of map)
// so corner gathers hit the local 4 MB L2 instead of the LLC. Wave w handles bins
// w, w+8, ...; 64 lanes cover 256 channels as ushort4; branchless, 16 loads in flight.
__global__ __launch_bounds__(512, 4) void roialign_bf16(const unsigned short* __restrict__ feat,
                                                        const float* __restrict__ rois,
                                                        const int* __restrict__ perm,
                                                        float* __restrict__ out) {
    __shared__ float sbuf[NBIN * LSTRIDE];

    const int bid = blockIdx.x;
    const int n   = perm[((bid & 7) << 6) | (bid >> 3)];
    const int t   = threadIdx.x;
    const int w   = t >> 6;
    const int cq  = t & 63;

    const RoiParams p = load_roi(rois, n);
    const ushort4* f4 = (const ushort4*)feat;

    for (int bin = w; bin < NBIN; bin += 8) {
        const int ph = bin / 7;
        const int pw = bin - ph * 7;

        float wt[16];
        int   ix[16];
        #pragma unroll
        for (int s = 0; s < 4; ++s) {
            float wts[4]; int pix[4];
            sample_wix(p, ph, pw, s, wts, pix);
            #pragma unroll
            for (int k = 0; k < 4; ++k) {
                wt[s * 4 + k] = wts[k];
                ix[s * 4 + k] = pix[k] * 64 + cq;
            }
        }

        ushort4 v[16];
        #pragma unroll
        for (int i = 0; i < 16; ++i) v[i] = f4[ix[i]];

        float ax = 0.f, ay = 0.f, az = 0.f, aw = 0.f;
        #pragma unroll
        for (int i = 0; i < 16; ++i) {
            ax += wt[i] * bf2f(v[i].x);
            ay += wt[i] * bf2f(v[i].y);
            az += wt[i] * bf2f(v[i].z);
            aw += wt[i] * bf2f(v[i].w);
        }

        float4 res; res.x = ax; res.y = ay; res.z = az; res.w = aw;
        *(float4*)(&sbuf[bin * LSTRIDE + cq * 4]) = res;
    }

    __syncthreads();

    // coalesced writeout: out[n][c][ph][pw], flat e = c*49 + bin
    const size_t obase = (size_t)n * (Cc * NBIN);
    for (int e = t; e < Cc * NBIN; e += 512) {
        const int c  = e / NBIN;
        const int bi = e - c * NBIN;
        out[obase + e] = sbuf[bi * LSTRIDE + c];
    }
}

// ---------------- fp32 NCHW fallback (only if ws too small) ----------------
__global__ __launch_bounds__(256) void roialign_nchw(const float* __restrict__ feat,
                                                     const float* __restrict__ rois,
                                                     float* __restrict__ out) {
    __shared__ float sbuf[NBIN * LSTRIDE];
    const int n = blockIdx.x, t = threadIdx.x;
    const int g = t >> 6, cq = t & 63;
    const RoiParams p = load_roi(rois, n);
    for (int bin = g; bin < NBIN; bin += 4) {
        const int ph = bin / 7, pw = bin - ph * 7;
        float acc[4] = {0.f, 0.f, 0.f, 0.f};
        for (int s = 0; s < 4; ++s) {
            float wts[4]; int pix[4];
            sample_wix(p, ph, pw, s, wts, pix);
            #pragma unroll
            for (int i = 0; i < 4; ++i) {
                const size_t cb = (size_t)(p.b * Cc + cq * 4 + i) * HWn;
                acc[i] += wts[0] * feat[cb + pix[0] - p.b * HWn] +
                          wts[1] * feat[cb + pix[1] - p.b * HWn] +
                          wts[2] * feat[cb + pix[2] - p.b * HWn] +
                          wts[3] * feat[cb + pix[3] - p.b * HWn];
            }
        }
        #pragma unroll
        for (int i = 0; i < 4; ++i) sbuf[bin * LSTRIDE + cq * 4 + i] = acc[i];
    }
    __syncthreads();
    const size_t obase = (size_t)n * (Cc * NBIN);
    for (int e = t; e < Cc * NBIN; e += 256) {
        const int c = e / NBIN, bi = e - c * NBIN;
        out[obase + e] = sbuf[bi * LSTRIDE + c];
    }
}

extern "C" void kernel_launch(void* const* d_in, const int* in_sizes, int n_in,
                              void* d_out, int out_size, void* d_ws, size_t ws_size,
                              hipStream_t stream) {
    const float* inputs = (const float*)d_in[0];
    const float* rois   = (const float*)d_in[1];
    float* out = (float*)d_out;

    const size_t need = MAP_BYTES + NROI * sizeof(int);
    if (d_ws != nullptr && ws_size >= need) {
        unsigned short* nhwc = (unsigned short*)d_ws;
        int* perm = (int*)((char*)d_ws + MAP_BYTES);
        sort_rois<<<1, 512, 0, stream>>>(rois, perm);
        dim3 tg(HWn / 64, Cc / 64, Bc);
        transpose_to_bf16_nhwc<<<tg, 256, 0, stream>>>(inputs, nhwc);
        roialign_bf16<<<NROI, 512, 0, stream>>>(nhwc, rois, perm, out);
    } else {
        roialign_nchw<<<NROI, 256, 0, stream>>>(inputs, rois, out);
    }
}

// Round 9
// 45.557 us; speedup vs baseline: 1.1078x; 1.1078x over previous
//
#include <hip/hip_runtime.h>

#define Bc   2
#define Cc   256
#define Hc   200
#define Wc   200
#define NROI 512
#define NBIN 49
#define HWn  (Hc * Wc)
#define LSTRIDE 260   // floats; 49*260*4 = 50,960 B LDS

// ---- bf16 helpers (RNE) ----
__device__ inline unsigned short f2bf(float f) {
    unsigned int u = __float_as_uint(f);
    return (unsigned short)((u + 0x7FFFu + ((u >> 16) & 1u)) >> 16);
}
__device__ inline float bf2f(unsigned short u) {
    return __uint_as_float(((unsigned int)u) << 16);
}

struct RoiParams { int b; float cx, cy, rw, rh, cs, sn, bh, bw; };

__device__ inline RoiParams load_roi(const float* rois, int n) {
    RoiParams p;
    const float* r = rois + n * 6;
    p.b  = (int)r[0];
    p.cx = r[1] * 0.25f;  p.cy = r[2] * 0.25f;
    p.rw = fmaxf(r[3] * 0.25f, 1.0f);
    p.rh = fmaxf(r[4] * 0.25f, 1.0f);
    p.cs = cosf(r[5]);    p.sn = sinf(r[5]);
    p.bh = p.rh * (1.0f / 7.0f);
    p.bw = p.rw * (1.0f / 7.0f);
    return p;
}

// per-sample coords -> 4 corner weights (validity+mean folded) + 4 pixel indices
__device__ inline void sample_wix(const RoiParams& p, int ph, int pw, int s,
                                  float* wt, int* pix) {
    const float sy = (s >> 1) ? 0.75f : 0.25f;
    const float sx = (s & 1)  ? 0.75f : 0.25f;
    const float yy = -0.5f * p.rh + ((float)ph + sy) * p.bh;
    const float xx = -0.5f * p.rw + ((float)pw + sx) * p.bw;
    float y = yy * p.cs - xx * p.sn + p.cy;
    float x = yy * p.sn + xx * p.cs + p.cx;
    const bool valid = (y > -1.0f) && (y < (float)Hc) && (x > -1.0f) && (x < (float)Wc);
    y = fmaxf(y, 0.0f); x = fmaxf(x, 0.0f);
    int yl = (int)y, xl = (int)x;
    const bool hiy = yl >= Hc - 1, hix = xl >= Wc - 1;
    yl = min(yl, Hc - 1); xl = min(xl, Wc - 1);
    const int yh = hiy ? (Hc - 1) : (yl + 1);
    const int xh = hix ? (Wc - 1) : (xl + 1);
    const float ly = hiy ? 0.0f : (y - (float)yl);
    const float lx = hix ? 0.0f : (x - (float)xl);
    const float hy = 1.0f - ly, hx = 1.0f - lx;
    const float vm = valid ? 0.25f : 0.0f;
    wt[0] = vm * hy * hx;  wt[1] = vm * hy * lx;
    wt[2] = vm * ly * hx;  wt[3] = vm * ly * lx;
    const int rl = (p.b * Hc + yl) * Wc;
    const int rt = (p.b * Hc + yh) * Wc;
    pix[0] = rl + xl;  pix[1] = rl + xh;
    pix[2] = rt + xl;  pix[3] = rt + xh;
}

// ---------------- NCHW fp32 -> NHWC bf16 transpose (64x64 LDS tile) ----------------
__global__ __launch_bounds__(256) void transpose_to_bf16_nhwc(const float* __restrict__ in,
                                                              unsigned short* __restrict__ out) {
    __shared__ unsigned short tile[64][65];
    const int b   = blockIdx.z;
    const int hw0 = blockIdx.x * 64;
    const int c0  = blockIdx.y * 64;
    const int tx  = threadIdx.x & 63;
    const int ty  = threadIdx.x >> 6;

    #pragma unroll
    for (int i = ty; i < 64; i += 4) {
        float v = in[(size_t)(b * Cc + c0 + i) * HWn + hw0 + tx];
        tile[i][tx] = f2bf(v);   // channel = c0+i, hw = hw0+tx
    }
    __syncthreads();

    const int j  = threadIdx.x & 31;    // channel pair -> c0+2j, c0+2j+1
    const int r0 = threadIdx.x >> 5;    // 0..7
    unsigned int* out32 = (unsigned int*)out;
    #pragma unroll
    for (int r = r0; r < 64; r += 8) {
        unsigned int lo = tile[2 * j][r];
        unsigned int hi = tile[2 * j + 1][r];
        // normal (allocating) store: the map is re-read by the main kernel
        out32[((size_t)(b * HWn + hw0 + r) * Cc + c0) / 2 + j] = lo | (hi << 16);
    }
}

// ---------------- main rotated roi-align kernel (round-4 structure) ----------------
// One block (512 thr = 8 waves) per roi; wave w handles bins w, w+8, ...;
// 64 lanes cover 256 channels as ushort4. Branchless (validity+mean folded into
// weights); all 16 corner loads of a bin issue back-to-back. Output staged in
// LDS, then written fully coalesced with NON-TEMPORAL stores (write-once data;
// avoids evicting the gather map from L2).
__global__ __launch_bounds__(512, 4) void roialign_bf16(const unsigned short* __restrict__ feat,
                                                        const float* __restrict__ rois,
                                                        float* __restrict__ out) {
    __shared__ float sbuf[NBIN * LSTRIDE];

    const int n  = blockIdx.x;
    const int t  = threadIdx.x;
    const int w  = t >> 6;
    const int cq = t & 63;

    const RoiParams p = load_roi(rois, n);
    const ushort4* f4 = (const ushort4*)feat;

    for (int bin = w; bin < NBIN; bin += 8) {
        const int ph = bin / 7;
        const int pw = bin - ph * 7;

        float wt[16];
        int   ix[16];
        #pragma unroll
        for (int s = 0; s < 4; ++s) {
            float wts[4]; int pix[4];
            sample_wix(p, ph, pw, s, wts, pix);
            #pragma unroll
            for (int k = 0; k < 4; ++k) {
                wt[s * 4 + k] = wts[k];
                ix[s * 4 + k] = pix[k] * 64 + cq;
            }
        }

        ushort4 v[16];
        #pragma unroll
        for (int i = 0; i < 16; ++i) v[i] = f4[ix[i]];

        float ax = 0.f, ay = 0.f, az = 0.f, aw = 0.f;
        #pragma unroll
        for (int i = 0; i < 16; ++i) {
            ax += wt[i] * bf2f(v[i].x);
            ay += wt[i] * bf2f(v[i].y);
            az += wt[i] * bf2f(v[i].z);
            aw += wt[i] * bf2f(v[i].w);
        }

        float4 res; res.x = ax; res.y = ay; res.z = az; res.w = aw;
        *(float4*)(&sbuf[bin * LSTRIDE + cq * 4]) = res;
    }

    __syncthreads();

    // coalesced writeout: out[n][c][ph][pw], flat e = c*49 + bin
    const size_t obase = (size_t)n * (Cc * NBIN);
    for (int e = t; e < Cc * NBIN; e += 512) {
        const int c  = e / NBIN;
        const int bi = e - c * NBIN;
        __builtin_nontemporal_store(sbuf[bi * LSTRIDE + c], &out[obase + e]);
    }
}

// ---------------- fp32 NCHW fallback (only if ws too small) ----------------
__global__ __launch_bounds__(256) void roialign_nchw(const float* __restrict__ feat,
                                                     const float* __restrict__ rois,
                                                     float* __restrict__ out) {
    __shared__ float sbuf[NBIN * LSTRIDE];
    const int n = blockIdx.x, t = threadIdx.x;
    const int g = t >> 6, cq = t & 63;
    const RoiParams p = load_roi(rois, n);
    for (int bin = g; bin < NBIN; bin += 4) {
        const int ph = bin / 7, pw = bin - ph * 7;
        float acc[4] = {0.f, 0.f, 0.f, 0.f};
        for (int s = 0; s < 4; ++s) {
            float wts[4]; int pix[4];
            sample_wix(p, ph, pw, s, wts, pix);
            #pragma unroll
            for (int i = 0; i < 4; ++i) {
                const size_t cb = (size_t)(p.b * Cc + cq * 4 + i) * HWn;
                acc[i] += wts[0] * feat[cb + pix[0] - p.b * HWn] +
                          wts[1] * feat[cb + pix[1] - p.b * HWn] +
                          wts[2] * feat[cb + pix[2] - p.b * HWn] +
                          wts[3] * feat[cb + pix[3] - p.b * HWn];
            }
        }
        #pragma unroll
        for (int i = 0; i < 4; ++i) sbuf[bin * LSTRIDE + cq * 4 + i] = acc[i];
    }
    __syncthreads();
    const size_t obase = (size_t)n * (Cc * NBIN);
    for (int e = t; e < Cc * NBIN; e += 256) {
        const int c = e / NBIN, bi = e - c * NBIN;
        __builtin_nontemporal_store(sbuf[bi * LSTRIDE + c], &out[obase + e]);
    }
}

extern "C" void kernel_launch(void* const* d_in, const int* in_sizes, int n_in,
                              void* d_out, int out_size, void* d_ws, size_t ws_size,
                              hipStream_t stream) {
    const float* inputs = (const float*)d_in[0];
    const float* rois   = (const float*)d_in[1];
    float* out = (float*)d_out;

    const size_t need = (size_t)Bc * HWn * Cc * sizeof(unsigned short);
    if (d_ws != nullptr && ws_size >= need) {
        unsigned short* nhwc = (unsigned short*)d_ws;
        dim3 tg(HWn / 64, Cc / 64, Bc);
        transpose_to_bf16_nhwc<<<tg, 256, 0, stream>>>(inputs, nhwc);
        roialign_bf16<<<NROI, 512, 0, stream>>>(nhwc, rois, out);
    } else {
        roialign_nchw<<<NROI, 256, 0, stream>>>(inputs, rois, out);
    }
}